// Round 5
// baseline (398.907 us; speedup 1.0000x reference)
//
#include <hip/hip_runtime.h>
#include <hip/hip_cooperative_groups.h>
#include <math.h>
namespace cg = cooperative_groups;

#define NATOMS 1280
#define NHEAD 4
#define DHEAD 16
#define EEDGE 5120
#define MKV 12800
#define NLAYERS 4
#define NGRAPH 32
#define NPG 40      // atoms per graph
#define MPG 400     // kv per graph
#define QH 20       // q rows per attention block (half graph)
#define NBLK 256
#define NTHR 1024

// LDS: one union, phases alternate. attn variant = 103 KB -> 1 block/CU.
union Smem {
  struct {                       // GEMM phases
    float aT[64][132];           // A tile transposed [k][row<=128], padded
    float wS[64][64];
  } g;
  struct {                       // attention phase
    float aggS[QH][64];
    float hS[QH][64];
    float Qs[QH][16];            // later reused as o_head
    float KT[16][404];           // K head-slice transposed [d][k], padded
    float VT[16][404];
    float P[QH][400];
    float part[8][QH][16];       // PV k-split partials
    float lsum[QH];
  } a;
};

__global__ __launch_bounds__(NTHR, 1) void mega_kernel(
    const float* __restrict__ x, const float* __restrict__ edge_attr,
    const float* __restrict__ Kin, const float* __restrict__ Vin,
    const float* __restrict__ We, const float* __restrict__ Wm,
    const float* __restrict__ Wq, const float* __restrict__ Wk,
    const float* __restrict__ Wv, const float* __restrict__ Wo,
    const int* __restrict__ src, const int* __restrict__ dst,
    float* __restrict__ Kh, float* __restrict__ Vh, float* __restrict__ EW,
    float* __restrict__ agg, float* __restrict__ xA, float* __restrict__ xB,
    float* __restrict__ out) {
  cg::grid_group grid = cg::this_grid();
  __shared__ Smem sm;
  const int t = threadIdx.x;
  const int b = blockIdx.x;
  const int gtid = b * NTHR + t;
  const int GT = NBLK * NTHR;

  // ---------- phase 0a: zero agg (all layers) ----------
  for (int i = gtid; i < NLAYERS * NATOMS * 64; i += GT) agg[i] = 0.f;

  // ---------- phase 0b: EW[l] = edge_attr @ We[l], 64-row tiles ----------
  for (int tid = b; tid < NLAYERS * (EEDGE / 64); tid += NBLK) {
    int l = tid / (EEDGE / 64), et = tid % (EEDGE / 64);
    const float* A = edge_attr + (size_t)et * 64 * 16;
    const float* W = We + l * 1024;
    float* C = EW + ((size_t)l * EEDGE + et * 64) * 64;
    __syncthreads();
    if (t < 256) {
      int r = t >> 2, c0 = (t & 3) * 4;
      float4 v = *(const float4*)(A + r * 16 + c0);
      sm.g.aT[c0 + 0][r] = v.x; sm.g.aT[c0 + 1][r] = v.y;
      sm.g.aT[c0 + 2][r] = v.z; sm.g.aT[c0 + 3][r] = v.w;
      float4 w = ((const float4*)W)[t];
      *(float4*)&sm.g.wS[t >> 4][(t & 15) * 4] = w;
    }
    __syncthreads();
    int rb = t >> 4, cb = (t & 15) * 4;   // 64 rows x 16 col-groups = 1024
    float acc0 = 0.f, acc1 = 0.f, acc2 = 0.f, acc3 = 0.f;
#pragma unroll
    for (int k = 0; k < 16; ++k) {
      float a0 = sm.g.aT[k][rb];
      float4 w = *(const float4*)&sm.g.wS[k][cb];
      acc0 += a0 * w.x; acc1 += a0 * w.y; acc2 += a0 * w.z; acc3 += a0 * w.w;
    }
    *(float4*)(C + (size_t)rb * 64 + cb) = make_float4(acc0, acc1, acc2, acc3);
  }

  // ---------- phase 0c: Kh/Vh = {K,V} @ {Wk,Wv}[l], 128-row tiles ----------
  for (int tid = b; tid < 8 * (MKV / 128); tid += NBLK) {
    int gy = tid / (MKV / 128), rt = tid % (MKV / 128);
    int which = gy >> 2, l = gy & 3;
    const float* A = (which ? Vin : Kin) + (size_t)rt * 128 * 64;
    const float* W = (which ? Wv : Wk) + l * 4096;
    float* C = (which ? Vh : Kh) + ((size_t)l * MKV + rt * 128) * 64;
    __syncthreads();
    for (int i = t; i < 2048; i += NTHR) {   // 128 rows x 16 float4
      int r = i >> 4, c0 = (i & 15) * 4;
      float4 v = *(const float4*)(A + r * 64 + c0);
      sm.g.aT[c0 + 0][r] = v.x; sm.g.aT[c0 + 1][r] = v.y;
      sm.g.aT[c0 + 2][r] = v.z; sm.g.aT[c0 + 3][r] = v.w;
    }
    for (int i = t; i < 1024; i += NTHR) {
      float4 v = ((const float4*)W)[i];
      *(float4*)&sm.g.wS[i >> 4][(i & 15) * 4] = v;
    }
    __syncthreads();
    int rb = (t >> 4) * 2, cb = (t & 15) * 4;
    float acc[2][4] = {};
#pragma unroll 8
    for (int k = 0; k < 64; ++k) {
      float2 a2 = *(const float2*)&sm.g.aT[k][rb];
      float4 w = *(const float4*)&sm.g.wS[k][cb];
      acc[0][0] += a2.x * w.x; acc[0][1] += a2.x * w.y;
      acc[0][2] += a2.x * w.z; acc[0][3] += a2.x * w.w;
      acc[1][0] += a2.y * w.x; acc[1][1] += a2.y * w.y;
      acc[1][2] += a2.y * w.z; acc[1][3] += a2.y * w.w;
    }
    *(float4*)(C + (size_t)rb * 64 + cb) =
        make_float4(acc[0][0], acc[0][1], acc[0][2], acc[0][3]);
    *(float4*)(C + (size_t)(rb + 1) * 64 + cb) =
        make_float4(acc[1][0], acc[1][1], acc[1][2], acc[1][3]);
  }

  grid.sync();

  // ---------- layers ----------
  const float* xin = x;
  float* bufs[NLAYERS] = {xA, xB, xA, out};
  for (int l = 0; l < NLAYERS; ++l) {
    float* xout = bufs[l];
    const float* EWl = EW + (size_t)l * EEDGE * 64;
    float* aggl = agg + (size_t)l * NATOMS * 64;
    const float* Wm_l = Wm + l * 4096;
    const float* Wq_l = Wq + l * 4096;
    const float* Wo_l = Wo + l * 4096;
    const float* Kh_l = Kh + (size_t)l * MKV * 64;
    const float* Vh_l = Vh + (size_t)l * MKV * 64;

    // ---- edge messages + scatter-add + residual init of xout ----
    for (int i = gtid; i < EEDGE * 64; i += GT) {
      if (i < NATOMS * 64) xout[i] = xin[i];
      int e = i >> 6, f = i & 63;
      float m = xin[src[e] * 64 + f] + EWl[i];
      m = m / (1.f + __expf(-m));   // silu
      atomicAdd(&aggl[dst[e] * 64 + f], m);
    }
    grid.sync();

    // ---- fused attention: block b -> (graph, head, q-half) ----
    {
      const int g = b >> 3, hd = (b >> 1) & 3, qh = b & 1;
      const int hoff = hd * DHEAD;
      const int qbase = g * NPG + qh * QH;
      const int kbase = g * MPG;

      for (int i = t; i < QH * 64; i += NTHR)
        sm.a.aggS[i >> 6][i & 63] = aggl[(qbase + (i >> 6)) * 64 + (i & 63)];
      __syncthreads();

      // h = xin + aggS @ Wm
      for (int i = t; i < QH * 64; i += NTHR) {
        int q = i >> 6, f = i & 63;
        float acc = xin[(qbase + q) * 64 + f];
#pragma unroll 16
        for (int k = 0; k < 64; ++k) acc += sm.a.aggS[q][k] * Wm_l[k * 64 + f];
        sm.a.hS[q][f] = acc;
      }
      __syncthreads();

      // Q_head = (h @ Wq slice) * 0.25 ; stage K^T and V^T head-slices
      for (int i = t; i < QH * 16; i += NTHR) {
        int q = i >> 4, d = i & 15;
        float acc = 0.f;
#pragma unroll 16
        for (int k = 0; k < 64; ++k) acc += sm.a.hS[q][k] * Wq_l[k * 64 + hoff + d];
        sm.a.Qs[q][d] = acc * 0.25f;
      }
      for (int i = t; i < MPG * DHEAD; i += NTHR) {
        int k = i >> 4, d = i & 15;
        sm.a.KT[d][k] = Kh_l[(size_t)(kbase + k) * 64 + hoff + d];
        sm.a.VT[d][k] = Vh_l[(size_t)(kbase + k) * 64 + hoff + d];
      }
      __syncthreads();

      // scores: P[q][k0..k0+3] via float4 along k (conflict-free)
      for (int c = t; c < QH * 100; c += NTHR) {
        int q = c / 100, k0 = (c % 100) * 4;
        float4 a4 = make_float4(0.f, 0.f, 0.f, 0.f);
#pragma unroll
        for (int d = 0; d < 16; ++d) {
          float qv = sm.a.Qs[q][d];
          float4 kv = *(const float4*)&sm.a.KT[d][k0];
          a4.x += qv * kv.x; a4.y += qv * kv.y;
          a4.z += qv * kv.z; a4.w += qv * kv.w;
        }
        *(float4*)&sm.a.P[q][k0] = a4;
      }
      __syncthreads();

      // softmax rows (unnormalized exp + row sum)
      {
        int w = t >> 6, lane = t & 63;
        for (int q = w; q < QH; q += 16) {
          float mx = -1e30f;
          for (int k = lane; k < MPG; k += 64) mx = fmaxf(mx, sm.a.P[q][k]);
          for (int off = 32; off; off >>= 1) mx = fmaxf(mx, __shfl_xor(mx, off));
          float s = 0.f;
          for (int k = lane; k < MPG; k += 64) {
            float p = __expf(sm.a.P[q][k] - mx);
            sm.a.P[q][k] = p;
            s += p;
          }
          for (int off = 32; off; off >>= 1) s += __shfl_xor(s, off);
          if (lane == 0) sm.a.lsum[q] = s;
        }
      }
      __syncthreads();

      // PV, 8-way k-split
      {
        int ks = t >> 7, j = t & 127, k0 = ks * 50;
        for (int pair = j; pair < QH * 16; pair += 128) {
          int q = pair >> 4, d = pair & 15;
          float acc = 0.f;
          for (int k = k0; k < k0 + 50; ++k)
            acc += sm.a.P[q][k] * sm.a.VT[d][k];
          sm.a.part[ks][q][d] = acc;
        }
      }
      __syncthreads();

      // reduce partials + normalize -> reuse Qs as o_head
      if (t < QH * 16) {
        int q = t >> 4, d = t & 15;
        float o = 0.f;
#pragma unroll
        for (int ks = 0; ks < 8; ++ks) o += sm.a.part[ks][q][d];
        sm.a.Qs[q][d] = o / sm.a.lsum[q];
      }
      __syncthreads();

      // out-projection partial for this head -> atomicAdd into xout
      for (int i = t; i < QH * 64; i += NTHR) {
        int q = i >> 6, f = i & 63;
        float acc = 0.f;
#pragma unroll
        for (int d = 0; d < DHEAD; ++d)
          acc += sm.a.Qs[q][d] * Wo_l[(hoff + d) * 64 + f];
        atomicAdd(&xout[(qbase + q) * 64 + f], acc);
      }
    }
    if (l < NLAYERS - 1) grid.sync();
    xin = xout;
  }
}

extern "C" void kernel_launch(void* const* d_in, const int* in_sizes, int n_in,
                              void* d_out, int out_size, void* d_ws, size_t ws_size,
                              hipStream_t stream) {
  const float* x        = (const float*)d_in[0];
  const float* edge_attr= (const float*)d_in[1];
  const float* K        = (const float*)d_in[2];
  const float* V        = (const float*)d_in[3];
  const float* We       = (const float*)d_in[4];
  const float* Wm       = (const float*)d_in[5];
  const float* Wq       = (const float*)d_in[6];
  const float* Wk       = (const float*)d_in[7];
  const float* Wv       = (const float*)d_in[8];
  const float* Wo       = (const float*)d_in[9];
  const int*   eidx     = (const int*)d_in[10];
  const int*   src      = eidx;
  const int*   dst      = eidx + EEDGE;

  float* w    = (float*)d_ws;
  float* Kh   = w;                                   // 4*12800*64
  float* Vh   = Kh + (size_t)NLAYERS * MKV * 64;     // 4*12800*64
  float* EW   = Vh + (size_t)NLAYERS * MKV * 64;     // 4*5120*64
  float* agg  = EW + (size_t)NLAYERS * EEDGE * 64;   // 4*1280*64
  float* xA   = agg + (size_t)NLAYERS * NATOMS * 64;
  float* xB   = xA + NATOMS * 64;
  float* out  = (float*)d_out;

  void* args[] = {&x, &edge_attr, &K, &V, &We, &Wm, &Wq, &Wk, &Wv, &Wo,
                  &src, &dst, &Kh, &Vh, &EW, &agg, &xA, &xB, &out};
  hipLaunchCooperativeKernel((void*)mega_kernel, dim3(NBLK), dim3(NTHR),
                             args, 0, stream);
}

// Round 6
// 126.973 us; speedup vs baseline: 3.1417x; 3.1417x over previous
//
#include <hip/hip_runtime.h>
#include <hip/hip_bf16.h>
#include <math.h>

#define NATOMS 1280
#define NHEAD 4
#define DHEAD 16
#define EEDGE 5120
#define MKV 12800
#define NLAYERS 4
#define NGRAPH 32
#define NPG 40      // atoms per graph
#define MPG 400     // kv per graph
#define QH 20       // q rows per attention block (half graph)

// ---- one precompute kernel: agg zero + EW GEMM + KV GEMM --------------------
// blocks [0,320): EW tiles; [320,1120): KV tiles; [1120,1200): agg zeroing
__global__ __launch_bounds__(256) void precompute_kernel(
    const float* __restrict__ edge_attr, const float* __restrict__ Kin,
    const float* __restrict__ Vin, const float* __restrict__ We,
    const float* __restrict__ Wk, const float* __restrict__ Wv,
    float* __restrict__ EW, float* __restrict__ Kh, float* __restrict__ Vh,
    float* __restrict__ agg) {
  __shared__ float aT[64][132];  // A tile transposed [k][row], padded
  __shared__ float wS[64][64];
  const int b = blockIdx.x, t = threadIdx.x;

  if (b < 320) {  // ---- EW[l] = edge_attr @ We[l], 64-row tiles, K=16 ----
    int l = b / 80, et = b % 80;
    const float* A = edge_attr + (size_t)et * 64 * 16;
    const float* W = We + l * 1024;
    float* C = EW + ((size_t)l * EEDGE + et * 64) * 64;
    {
      int r = t >> 2, c0 = (t & 3) * 4;
      float4 v = *(const float4*)(A + r * 16 + c0);
      aT[c0 + 0][r] = v.x; aT[c0 + 1][r] = v.y;
      aT[c0 + 2][r] = v.z; aT[c0 + 3][r] = v.w;
      float4 w = ((const float4*)W)[t];
      *(float4*)&wS[t >> 4][(t & 15) * 4] = w;
    }
    __syncthreads();
    const int rb = (t >> 4) * 4, cb = (t & 15) * 4;
    float acc[4][4] = {};
#pragma unroll
    for (int k = 0; k < 16; ++k) {
      float4 a = *(const float4*)&aT[k][rb];
      float4 w = *(const float4*)&wS[k][cb];
      acc[0][0] += a.x * w.x; acc[0][1] += a.x * w.y; acc[0][2] += a.x * w.z; acc[0][3] += a.x * w.w;
      acc[1][0] += a.y * w.x; acc[1][1] += a.y * w.y; acc[1][2] += a.y * w.z; acc[1][3] += a.y * w.w;
      acc[2][0] += a.z * w.x; acc[2][1] += a.z * w.y; acc[2][2] += a.z * w.z; acc[2][3] += a.z * w.w;
      acc[3][0] += a.w * w.x; acc[3][1] += a.w * w.y; acc[3][2] += a.w * w.z; acc[3][3] += a.w * w.w;
    }
#pragma unroll
    for (int i = 0; i < 4; ++i)
      *(float4*)(C + (size_t)(rb + i) * 64 + cb) =
          make_float4(acc[i][0], acc[i][1], acc[i][2], acc[i][3]);
  } else if (b < 1120) {  // ---- Kh/Vh = {K,V} @ {Wk,Wv}[l], 128-row tiles ----
    int tid = b - 320;
    int gy = tid / 100, rt = tid % 100;
    int which = gy >> 2, l = gy & 3;
    const float* A = (which ? Vin : Kin) + (size_t)rt * 128 * 64;
    const float* W = (which ? Wv : Wk) + l * 4096;
    float* C = (which ? Vh : Kh) + ((size_t)l * MKV + rt * 128) * 64;
    for (int i = t; i < 2048; i += 256) {  // 128 rows x 16 float4, transpose
      int r = i >> 4, c0 = (i & 15) * 4;
      float4 v = *(const float4*)(A + r * 64 + c0);
      aT[c0 + 0][r] = v.x; aT[c0 + 1][r] = v.y;
      aT[c0 + 2][r] = v.z; aT[c0 + 3][r] = v.w;
    }
    for (int i = t; i < 1024; i += 256) {
      float4 v = ((const float4*)W)[i];
      *(float4*)&wS[i >> 4][(i & 15) * 4] = v;
    }
    __syncthreads();
    const int rb = (t >> 4) * 8, cb = (t & 15) * 4;
    float acc[8][4] = {};
#pragma unroll 4
    for (int k = 0; k < 64; ++k) {
      float4 a0 = *(const float4*)&aT[k][rb];
      float4 a1 = *(const float4*)&aT[k][rb + 4];
      float4 w = *(const float4*)&wS[k][cb];
      acc[0][0] += a0.x * w.x; acc[0][1] += a0.x * w.y; acc[0][2] += a0.x * w.z; acc[0][3] += a0.x * w.w;
      acc[1][0] += a0.y * w.x; acc[1][1] += a0.y * w.y; acc[1][2] += a0.y * w.z; acc[1][3] += a0.y * w.w;
      acc[2][0] += a0.z * w.x; acc[2][1] += a0.z * w.y; acc[2][2] += a0.z * w.z; acc[2][3] += a0.z * w.w;
      acc[3][0] += a0.w * w.x; acc[3][1] += a0.w * w.y; acc[3][2] += a0.w * w.z; acc[3][3] += a0.w * w.w;
      acc[4][0] += a1.x * w.x; acc[4][1] += a1.x * w.y; acc[4][2] += a1.x * w.z; acc[4][3] += a1.x * w.w;
      acc[5][0] += a1.y * w.x; acc[5][1] += a1.y * w.y; acc[5][2] += a1.y * w.z; acc[5][3] += a1.y * w.w;
      acc[6][0] += a1.z * w.x; acc[6][1] += a1.z * w.y; acc[6][2] += a1.z * w.z; acc[6][3] += a1.z * w.w;
      acc[7][0] += a1.w * w.x; acc[7][1] += a1.w * w.y; acc[7][2] += a1.w * w.z; acc[7][3] += a1.w * w.w;
    }
#pragma unroll
    for (int i = 0; i < 8; ++i)
      *(float4*)(C + (size_t)(rb + i) * 64 + cb) =
          make_float4(acc[i][0], acc[i][1], acc[i][2], acc[i][3]);
  } else {  // ---- zero agg (all layers): 4*1280*64 floats = 81920 float4 ----
    int i = (b - 1120) * 256 + t;
    float4 z = make_float4(0.f, 0.f, 0.f, 0.f);
    for (int j = i; j < NLAYERS * NATOMS * 16; j += 80 * 256)
      ((float4*)agg)[j] = z;
  }
}

// -- per layer: edge messages + scatter-add, AND init xout = xin (residual) ---
__global__ void edge_copy_kernel(const float* __restrict__ xin,
                                 const float* __restrict__ EWl,
                                 const int* __restrict__ src,
                                 const int* __restrict__ dst,
                                 float* __restrict__ agg,
                                 float* __restrict__ xout) {
  int idx = blockIdx.x * 256 + threadIdx.x;  // covers E*64 = 327680
  if (idx < NATOMS * 64) xout[idx] = xin[idx];
  int e = idx >> 6, f = idx & 63;
  float m = xin[src[e] * 64 + f] + EWl[idx];
  m = m / (1.f + __expf(-m));  // silu
  atomicAdd(&agg[dst[e] * 64 + f], m);
}

// -- fused attention, conflict-free LDS layouts.
//    one block per (graph, head, q-half): 32*4*2 = 256 blocks x 512 threads ---
__global__ __launch_bounds__(512) void fused_attn_kernel(
    const float* __restrict__ xin, const float* __restrict__ agg,
    const float* __restrict__ Wm, const float* __restrict__ Wq,
    const float* __restrict__ Wo, const float* __restrict__ Kh,
    const float* __restrict__ Vh, float* __restrict__ xout) {
  __shared__ union {
    float aggS[QH][64];          // used before h is built
    float part[8][QH][16];       // used at PV reduce
  } u;
  __shared__ float hS[QH][64];
  __shared__ float Qs[QH][16];   // Q*0.25, later reused as o_head
  __shared__ float KT[16][404];  // K head-slice transposed [d][k], padded
  __shared__ float VT[16][404];
  __shared__ float P[QH][400];
  __shared__ float lsum[QH];

  const int g = blockIdx.x, hd = blockIdx.y, qh = blockIdx.z;
  const int t = threadIdx.x;
  const int hoff = hd * DHEAD;
  const int qbase = g * NPG + qh * QH;
  const int kbase = g * MPG;

  // stage agg rows for this q-half
  for (int i = t; i < QH * 64; i += 512)
    u.aggS[i >> 6][i & 63] = agg[(qbase + (i >> 6)) * 64 + (i & 63)];
  __syncthreads();

  // h = xin + aggS @ Wm
  for (int i = t; i < QH * 64; i += 512) {
    int q = i >> 6, f = i & 63;
    float acc = xin[(qbase + q) * 64 + f];
#pragma unroll 16
    for (int k = 0; k < 64; ++k) acc += u.aggS[q][k] * Wm[k * 64 + f];
    hS[q][f] = acc;
  }
  __syncthreads();

  // Q_head = (h @ Wq slice) * 0.25 ; stage K^T, V^T head-slices
  for (int i = t; i < QH * 16; i += 512) {
    int q = i >> 4, d = i & 15;
    float acc = 0.f;
#pragma unroll 16
    for (int k = 0; k < 64; ++k) acc += hS[q][k] * Wq[k * 64 + hoff + d];
    Qs[q][d] = acc * 0.25f;
  }
  for (int i = t; i < MPG * DHEAD; i += 512) {
    int k = i >> 4, d = i & 15;   // global: 64B-coalesced per 16 lanes
    KT[d][k] = Kh[(size_t)(kbase + k) * 64 + hoff + d];
    VT[d][k] = Vh[(size_t)(kbase + k) * 64 + hoff + d];
  }
  __syncthreads();

  // scores: P[q][k], lane-consecutive k (all LDS stride-1, conflict-free)
  for (int i = t; i < QH * MPG; i += 512) {
    int q = i / MPG, k = i - q * MPG;
    float acc = 0.f;
#pragma unroll
    for (int d = 0; d < DHEAD; ++d) acc += Qs[q][d] * KT[d][k];
    P[q][k] = acc;
  }
  __syncthreads();

  // softmax rows (unnormalized exp + row sum); 8 waves
  {
    const int w = t >> 6, lane = t & 63;
    for (int q = w; q < QH; q += 8) {
      float mx = -1e30f;
      for (int k = lane; k < MPG; k += 64) mx = fmaxf(mx, P[q][k]);
      for (int off = 32; off; off >>= 1) mx = fmaxf(mx, __shfl_xor(mx, off));
      float s = 0.f;
      for (int k = lane; k < MPG; k += 64) {
        float p = __expf(P[q][k] - mx);
        P[q][k] = p;
        s += p;
      }
      for (int off = 32; off; off >>= 1) s += __shfl_xor(s, off);
      if (lane == 0) lsum[q] = s;
    }
  }
  __syncthreads();

  // PV: 8-way k-split, all 512 threads. wave ks owns k in [ks*50, ks*50+50)
  {
    const int ks = t >> 6, j = t & 63, k0 = ks * 50;
    for (int pair = j; pair < QH * 16; pair += 64) {
      int q = pair >> 4, d = pair & 15;
      float acc = 0.f;
      for (int k = k0; k < k0 + 50; ++k) acc += P[q][k] * VT[d][k];
      u.part[ks][q][d] = acc;
    }
  }
  __syncthreads();

  // reduce partials + normalize -> reuse Qs as o_head
  if (t < QH * 16) {
    int q = t >> 4, d = t & 15;
    float o = 0.f;
#pragma unroll
    for (int ks = 0; ks < 8; ++ks) o += u.part[ks][q][d];
    Qs[q][d] = o / lsum[q];
  }
  __syncthreads();

  // out-projection partial for this head -> atomicAdd into xout
  for (int i = t; i < QH * 64; i += 512) {
    int q = i >> 6, f = i & 63;
    float acc = 0.f;
#pragma unroll
    for (int d = 0; d < DHEAD; ++d) acc += Qs[q][d] * Wo[(hoff + d) * 64 + f];
    atomicAdd(&xout[(qbase + q) * 64 + f], acc);
  }
}

extern "C" void kernel_launch(void* const* d_in, const int* in_sizes, int n_in,
                              void* d_out, int out_size, void* d_ws, size_t ws_size,
                              hipStream_t stream) {
  const float* x        = (const float*)d_in[0];
  const float* edge_attr= (const float*)d_in[1];
  const float* K        = (const float*)d_in[2];
  const float* V        = (const float*)d_in[3];
  const float* We       = (const float*)d_in[4];
  const float* Wm       = (const float*)d_in[5];
  const float* Wq       = (const float*)d_in[6];
  const float* Wk       = (const float*)d_in[7];
  const float* Wv       = (const float*)d_in[8];
  const float* Wo       = (const float*)d_in[9];
  const int*   eidx     = (const int*)d_in[10];
  const int*   src      = eidx;
  const int*   dst      = eidx + EEDGE;

  float* w    = (float*)d_ws;
  float* Kh   = w;                                   // 4*12800*64
  float* Vh   = Kh + (size_t)NLAYERS * MKV * 64;     // 4*12800*64
  float* EW   = Vh + (size_t)NLAYERS * MKV * 64;     // 4*5120*64
  float* agg  = EW + (size_t)NLAYERS * EEDGE * 64;   // 4*1280*64
  float* xA   = agg + (size_t)NLAYERS * NATOMS * 64;
  float* xB   = xA + NATOMS * 64;

  // one precompute kernel: agg zero + EW + Kh/Vh (all layers)
  precompute_kernel<<<1200, 256, 0, stream>>>(edge_attr, K, V, We, Wk, Wv,
                                              EW, Kh, Vh, agg);

  const float* xin = x;
  for (int l = 0; l < NLAYERS; ++l) {
    float* aggl = agg + (size_t)l * NATOMS * 64;
    float* xout = (l == NLAYERS - 1) ? (float*)d_out : ((l & 1) ? xB : xA);
    edge_copy_kernel<<<EEDGE * 64 / 256, 256, 0, stream>>>(
        xin, EW + (size_t)l * EEDGE * 64, src, dst, aggl, xout);
    fused_attn_kernel<<<dim3(NGRAPH, NHEAD, 2), 512, 0, stream>>>(
        xin, aggl, Wm + l * 4096, Wq + l * 4096, Wo + l * 4096,
        Kh + (size_t)l * MKV * 64, Vh + (size_t)l * MKV * 64, xout);
    xin = xout;
  }
}